// Round 5
// baseline (1164.473 us; speedup 1.0000x reference)
//
#include <hip/hip_runtime.h>
#include <hip/hip_bf16.h>
#include <math.h>
#include <stdint.h>

typedef unsigned int u32;
typedef unsigned long long u64;

#define NM   65536
#define HD   1024
#define KS   128
#define SQ   258
#define NH_  16
#define NL   4
#define NBIN 65536
#define CCAP 2048

using bf16x8 = __attribute__((ext_vector_type(8))) short;
using f32x4v = __attribute__((ext_vector_type(4))) float;

struct Ctrl { u32 b1, above1, T, candcnt; };

static constexpr size_t A256(size_t x){ return (x + 255) & ~(size_t)255; }

// ---- zeroed-at-launch region (ONE memset) ----
constexpr size_t OFF_H3   = 0;                                  // 3*NBIN u32
constexpr size_t OFF_C3   = OFF_H3 + (size_t)3*NBIN*4;          // 3*NBIN u32
constexpr size_t OFF_HS   = OFF_C3 + (size_t)3*NBIN*4;          // NBIN u32
constexpr size_t OFF_VP   = OFF_HS + (size_t)NBIN*4;            // 129 f32 (+pad)
constexpr size_t ZERO_BYTES = OFF_VP + 1024;
// ---- rest ----
constexpr size_t OFF_P3   = A256(ZERO_BYTES);                       // 3*(NBIN+1) u32
constexpr size_t OFF_K3   = A256(OFF_P3 + (size_t)3*(NBIN+1)*4);    // 3*NM u32
constexpr size_t OFF_L3   = A256(OFF_K3 + (size_t)3*NM*4);          // 3*NM u32
constexpr size_t OFF_KSC  = A256(OFF_L3 + (size_t)3*NM*4);          // NM u32
constexpr size_t OFF_CAND = A256(OFF_KSC + (size_t)NM*4);           // CCAP u64
constexpr size_t OFF_CTRL = A256(OFF_CAND + (size_t)CCAP*8);
constexpr size_t OFF_IDX  = A256(OFF_CTRL + 256);
constexpr size_t OFF_HM   = A256(OFF_IDX  + (size_t)KS*4);
constexpr size_t OFF_HT   = A256(OFF_HM   + (size_t)KS*HD*4);
constexpr size_t OFF_REW  = A256(OFF_HT   + (size_t)KS*HD*4);
constexpr size_t OFF_VECS = A256(OFF_REW  + (size_t)KS*4);
constexpr size_t OFF_LNB  = A256(OFF_VECS + (size_t)SQ*HD*4);
constexpr size_t OFF_QKV  = A256(OFF_LNB  + (size_t)SQ*HD*4);
constexpr size_t OFF_ATT  = A256(OFF_QKV  + (size_t)SQ*3*HD*4);
constexpr size_t OFF_FFH  = A256(OFF_ATT  + (size_t)SQ*HD*4);
constexpr size_t OFF_PART = A256(OFF_FFH  + (size_t)SQ*4*HD*4);   // 2 x 4*SQ*HD f32

// output layout (floats)
constexpr int OUT_NEXT = 257*HD;
constexpr int OUT_VP   = OUT_NEXT + KS*HD;
constexpr int OUT_LOSS = OUT_VP + 1;
constexpr int OUT_REWO = OUT_LOSS + KS;

__device__ __forceinline__ float gelu_f(float v){
  return 0.5f*v*(1.0f + erff(v*0.70710678118654752440f));
}

__device__ __forceinline__ short f2bf(float f){
  __hip_bfloat16 h = __float2bfloat16(f);
  short s;
  __builtin_memcpy(&s, &h, sizeof(short));
  return s;
}

__device__ __forceinline__ u32 fkey(float v){
  u32 b = __float_as_uint(v);
  return (b >> 31) ? ~b : (b | 0x80000000u);
}

// ----------------- scoring: fused xnorm + sim + keys + hist -----------------
__global__ __launch_bounds__(256) void k_sim2key(const float* __restrict__ mv, const float* __restrict__ x,
                                                 const float* __restrict__ surp, const float* __restrict__ noise,
                                                 u32* __restrict__ keys3, u32* __restrict__ hist3){
  __shared__ float xs[HD];
  __shared__ float red[256];
  int t = threadIdx.x;
  float s = 0.f;
  for(int i=t;i<HD;i+=256){ float v=x[i]; s += v*v; }
  red[t]=s; __syncthreads();
  for(int o=128;o>0;o>>=1){ if(t<o) red[t]+=red[t+o]; __syncthreads(); }
  float nrm = fmaxf(sqrtf(red[0]), 1e-8f);
  for(int i=t;i<HD;i+=256) xs[i] = x[i]/nrm;
  __syncthreads();
  int lane = t & 63, w = t >> 6;
  int row = blockIdx.x*4 + w;
  const float4* p = (const float4*)(mv + (size_t)row*HD);
  const float4* q = (const float4*)xs;
  float d=0.f, ss=0.f;
  #pragma unroll
  for(int r=0;r<4;++r){
    float4 v = p[lane + 64*r]; float4 u = q[lane + 64*r];
    d  += v.x*u.x + v.y*u.y + v.z*u.z + v.w*u.w;
    ss += v.x*v.x + v.y*v.y + v.z*v.z + v.w*v.w;
  }
  for(int off=32;off>0;off>>=1){ d += __shfl_xor(d,off,64); ss += __shfl_xor(ss,off,64); }
  if(lane==0){
    float sim = d / fmaxf(sqrtf(ss),1e-8f);
    float vals[3] = { surp[row], sim, noise[row] };
    #pragma unroll
    for(int a=0;a<3;++a){
      u32 k = fkey(vals[a]);
      keys3[(size_t)a*NM + row] = k;
      atomicAdd(&hist3[(size_t)a*NBIN + (k >> 16)], 1u);
    }
  }
}

// ----------------- tie-aware ranking -----------------
__global__ __launch_bounds__(1024) void k_scan3(const u32* __restrict__ hist3, u32* __restrict__ pref3){
  __shared__ u32 part[1024];
  const u32* hist = hist3 + (size_t)blockIdx.x*NBIN;
  u32* prefix = pref3 + (size_t)blockIdx.x*(NBIN+1);
  int t = threadIdx.x;
  u32 base = t*64, s = 0;
  for(int j=0;j<64;++j) s += hist[base+j];
  part[t] = s; __syncthreads();
  for(int off=1;off<1024;off<<=1){
    u32 v = (t >= off) ? part[t-off] : 0u;
    __syncthreads();
    part[t] += v;
    __syncthreads();
  }
  u32 run = part[t] - s;
  for(int j=0;j<64;++j){ prefix[base+j] = run; run += hist[base+j]; }
  if(t == 1023) prefix[NBIN] = run;
}

__global__ void k_scatter3(const u32* __restrict__ keys3, const u32* __restrict__ pref3,
                           u32* __restrict__ cnt3, u32* __restrict__ lo3){
  int i = blockIdx.x*256 + threadIdx.x;
  if(i >= NM) return;
  #pragma unroll
  for(int a=0;a<3;++a){
    u32 k = keys3[(size_t)a*NM + i];
    u32 b = k >> 16;
    u32 pos = pref3[(size_t)a*(NBIN+1) + b] + atomicAdd(&cnt3[(size_t)a*NBIN + b], 1u);
    lo3[(size_t)a*NM + pos] = k & 0xFFFFu;
  }
}

// rank (3 arrays) + score + score-key + score-hist, fused
__global__ void k_rank3score(const u32* __restrict__ keys3, const u32* __restrict__ pref3,
                             const u32* __restrict__ lo3, u32* __restrict__ keysS, u32* __restrict__ histS){
  int i = blockIdx.x*256 + threadIdx.x;
  if(i >= NM) return;
  float rr[3];
  #pragma unroll
  for(int a=0;a<3;++a){
    u32 k = keys3[(size_t)a*NM + i];
    u32 b = k >> 16, my = k & 0xFFFFu;
    const u32* pref = pref3 + (size_t)a*(NBIN+1);
    const u32* lo = lo3 + (size_t)a*NM;
    u32 s = pref[b], e = pref[b+1];
    u32 nl = 0, ne = 0;
    for(u32 j=s;j<e;++j){ u32 u = lo[j]; nl += (u < my); ne += (u == my); }
    u32 left = s + nl, right = left + ne;
    rr[a] = (float)(left + right - 1) * (1.0f/131072.0f);
  }
  float sc = __fadd_rn(__fadd_rn(__fmul_rn(rr[0],rr[0]), __fmul_rn(rr[1],rr[1])), __fmul_rn(rr[2],rr[2]));
  u32 k = __float_as_uint(sc);
  keysS[i] = k;
  atomicAdd(&histS[k >> 16], 1u);
}

// ----------------- top-k select (single radix level + exact sort) -----------------
__global__ __launch_bounds__(1024) void k_sel1(const u32* __restrict__ hist, Ctrl* ctrl){
  __shared__ u32 part[1024];
  int t = threadIdx.x;
  u32 base = t*64, s = 0;
  for(int j=0;j<64;++j) s += hist[base+j];
  part[t] = s; __syncthreads();
  for(int off=1;off<1024;off<<=1){
    u32 v = (t+off < 1024) ? part[t+off] : 0u;
    __syncthreads();
    part[t] += v;
    __syncthreads();
  }
  u32 above = part[t] - s;
  if(above < (u32)KS && above + s >= (u32)KS){
    u32 cum = above;
    for(int j=63;j>=0;--j){
      u32 c = hist[base+j];
      if(cum + c >= (u32)KS){
        ctrl->T = (u32)(base+j) << 16;   // bucket floor: collect whole threshold bucket
        ctrl->candcnt = 0;
        break;
      }
      cum += c;
    }
  }
}

__global__ void k_collect(const u32* __restrict__ keys, Ctrl* ctrl, u64* __restrict__ cand){
  int i = blockIdx.x*256 + threadIdx.x;
  if(i >= NM) return;
  u32 k = keys[i];
  if(k >= ctrl->T){
    u32 p = atomicAdd(&ctrl->candcnt, 1u);
    if(p < (u32)CCAP) cand[p] = ((u64)(~k) << 32) | (u32)i;
  }
}

__global__ __launch_bounds__(1024) void k_sortsel(const u64* __restrict__ cand, const Ctrl* ctrl, int* __restrict__ idx){
  __shared__ u64 sm[CCAP];
  int t = threadIdx.x;
  u32 n = ctrl->candcnt; if(n > (u32)CCAP) n = CCAP;
  for(int i=t;i<CCAP;i+=1024) sm[i] = (i < (int)n) ? cand[i] : 0xFFFFFFFFFFFFFFFFull;
  __syncthreads();
  for(int k=2;k<=CCAP;k<<=1){
    for(int j=k>>1;j>0;j>>=1){
      for(int i=t;i<CCAP;i+=1024){
        int ixj = i ^ j;
        if(ixj > i){
          bool up = ((i & k) == 0);
          u64 a = sm[i], b = sm[ixj];
          if((a > b) == up){ sm[i] = b; sm[ixj] = a; }
        }
      }
      __syncthreads();
    }
  }
  if(t < KS) idx[t] = (int)(sm[t] & 0xFFFFFFFFu);
}

// ----------------- gather: vecs odd rows (+pos), boundary rows, act hidden, outputs -----------------
__global__ void k_gather(const int* __restrict__ idx,
                         const float* __restrict__ mv, const float* __restrict__ mnv,
                         const float* __restrict__ mrew,
                         const int* __restrict__ aim, const int* __restrict__ ait,
                         const float* __restrict__ amw1, const float* __restrict__ amb1,
                         const float* __restrict__ atw1, const float* __restrict__ atb1,
                         const float* __restrict__ start, const float* __restrict__ x,
                         const float* __restrict__ pos,
                         float* __restrict__ vecs, float* __restrict__ outnext,
                         float* __restrict__ hm, float* __restrict__ ht,
                         float* __restrict__ rew, float* __restrict__ outrew){
  int k = blockIdx.x;
  int t = threadIdx.x;
  if(k < KS){
    int row = idx[k];
    const float* a = mv  + (size_t)row*HD;
    const float* b = mnv + (size_t)row*HD;
    const float* pz = pos + (size_t)(2*k+1)*HD;
    float* vr = vecs + (size_t)(2*k+1)*HD;
    for(int c=t;c<HD;c+=256){
      vr[c] = a[c] + pz[c];
      outnext[(size_t)k*HD+c] = b[c];
    }
    int am = aim[row], at = ait[row];
    for(int j=t;j<HD;j+=256){
      hm[(size_t)k*HD+j] = gelu_f(amw1[(size_t)j*9 + am] + amb1[j]);
      ht[(size_t)k*HD+j] = gelu_f(atw1[(size_t)j*4 + at] + atb1[j]);
    }
    if(t == 0){ float r = mrew[row]; rew[k] = r; outrew[k] = r; }
  } else {
    for(int c=t;c<HD;c+=256){
      vecs[c] = start[c] + pos[c];
      vecs[(size_t)(SQ-1)*HD + c] = x[c] + pos[(size_t)(SQ-1)*HD + c];
    }
  }
}

// ----------------- bf16 MFMA GEMM, double-buffered LDS, 1 barrier/K-step -----------------
// A: [M][lda] fp32, B: [N][K] fp32. 64x64 tile, 4 waves (2x2 of 32x32), BK=32.
// ACT: 0 none, 1 gelu, 2 gelu+row-dot(w2)->atomic vp (no C write). DIRECT: write C, else partials P[z].
template<int ACT, bool DIRECT>
__global__ __launch_bounds__(256) void gemm_k(const float* __restrict__ A, const float* __restrict__ B,
        const float* __restrict__ bias, float* __restrict__ P,
        const float* __restrict__ w2, float* __restrict__ vp,
        int M, int N, int K, int S, int nbm, int lda){
  u32 nwg = gridDim.x;
  u32 orig = blockIdx.x;
  u32 q = nwg >> 3, r8 = nwg & 7;
  u32 xcd = orig & 7, loc = orig >> 3;
  u32 swz = (xcd < r8 ? xcd*(q+1) : r8*(q+1) + (xcd-r8)*q) + loc;
  int bm = (int)(swz % (u32)nbm) * 64;
  u32 tmp = swz / (u32)nbm;
  int z  = DIRECT ? 0 : (int)(tmp % (u32)S);
  int bn = DIRECT ? (int)tmp * 64 : (int)(tmp / (u32)S) * 64;
  int Ks = K / S, kbeg = z*Ks;
  int nk = Ks >> 5;

  __shared__ short As[2*2048];
  __shared__ short Bs[2*2048];
  __shared__ float rsum[64];

  int t = threadIdx.x;
  int srow = t >> 2, sg = t & 3;
  int sgp = sg ^ ((srow >> 1) & 3);
  bool arow_ok = (bm + srow) < M;
  const float* ap = A + (size_t)(bm + srow)*lda + kbeg + sg*8;
  const float* bp = B + (size_t)(bn + srow)*K + kbeg + sg*8;
  int stoff = srow*32 + sgp*8;

  int lane = t & 63, w = t >> 6;
  int wm = (w >> 1)*32, wn = (w & 1)*32;
  int lr = lane & 15, lg = lane >> 4;
  int ra0 = wm + lr, ra1 = ra0 + 16;
  int rb0 = wn + lr, rb1 = rb0 + 16;
  int aoff0 = ra0*32 + (lg ^ ((ra0>>1)&3))*8;
  int aoff1 = ra1*32 + (lg ^ ((ra1>>1)&3))*8;
  int boff0 = rb0*32 + (lg ^ ((rb0>>1)&3))*8;
  int boff1 = rb1*32 + (lg ^ ((rb1>>1)&3))*8;

  f32x4v acc00 = {0,0,0,0}, acc01 = {0,0,0,0}, acc10 = {0,0,0,0}, acc11 = {0,0,0,0};

  // prologue: stage k=0 into buf0
  {
    float4 va0 = {0,0,0,0}, va1 = {0,0,0,0};
    if(arow_ok){ va0 = *(const float4*)ap; va1 = *(const float4*)(ap+4); }
    float4 vb0 = *(const float4*)bp;
    float4 vb1 = *(const float4*)(bp+4);
    ap += 32; bp += 32;
    bf16x8 sa, sb;
    sa[0]=f2bf(va0.x); sa[1]=f2bf(va0.y); sa[2]=f2bf(va0.z); sa[3]=f2bf(va0.w);
    sa[4]=f2bf(va1.x); sa[5]=f2bf(va1.y); sa[6]=f2bf(va1.z); sa[7]=f2bf(va1.w);
    sb[0]=f2bf(vb0.x); sb[1]=f2bf(vb0.y); sb[2]=f2bf(vb0.z); sb[3]=f2bf(vb0.w);
    sb[4]=f2bf(vb1.x); sb[5]=f2bf(vb1.y); sb[6]=f2bf(vb1.z); sb[7]=f2bf(vb1.w);
    *(bf16x8*)&As[stoff] = sa;
    *(bf16x8*)&Bs[stoff] = sb;
  }
  __syncthreads();

  for(int kk = 0; kk < nk; ++kk){
    int cur = (kk & 1) << 11;
    bool more = (kk + 1) < nk;
    float4 va0, va1, vb0, vb1;
    if(more){
      va0 = make_float4(0,0,0,0); va1 = make_float4(0,0,0,0);
      if(arow_ok){ va0 = *(const float4*)ap; va1 = *(const float4*)(ap+4); }
      vb0 = *(const float4*)bp;
      vb1 = *(const float4*)(bp+4);
      ap += 32; bp += 32;
    }
    bf16x8 a0 = *(const bf16x8*)&As[cur + aoff0];
    bf16x8 a1 = *(const bf16x8*)&As[cur + aoff1];
    bf16x8 b0 = *(const bf16x8*)&Bs[cur + boff0];
    bf16x8 b1 = *(const bf16x8*)&Bs[cur + boff1];
    acc00 = __builtin_amdgcn_mfma_f32_16x16x32_bf16(a0, b0, acc00, 0, 0, 0);
    acc01 = __builtin_amdgcn_mfma_f32_16x16x32_bf16(a0, b1, acc01, 0, 0, 0);
    acc10 = __builtin_amdgcn_mfma_f32_16x16x32_bf16(a1, b0, acc10, 0, 0, 0);
    acc11 = __builtin_amdgcn_mfma_f32_16x16x32_bf16(a1, b1, acc11, 0, 0, 0);
    if(more){
      int nxt = cur ^ 2048;
      bf16x8 sa, sb;
      sa[0]=f2bf(va0.x); sa[1]=f2bf(va0.y); sa[2]=f2bf(va0.z); sa[3]=f2bf(va0.w);
      sa[4]=f2bf(va1.x); sa[5]=f2bf(va1.y); sa[6]=f2bf(va1.z); sa[7]=f2bf(va1.w);
      sb[0]=f2bf(vb0.x); sb[1]=f2bf(vb0.y); sb[2]=f2bf(vb0.z); sb[3]=f2bf(vb0.w);
      sb[4]=f2bf(vb1.x); sb[5]=f2bf(vb1.y); sb[6]=f2bf(vb1.z); sb[7]=f2bf(vb1.w);
      *(bf16x8*)&As[nxt + stoff] = sa;
      *(bf16x8*)&Bs[nxt + stoff] = sb;
    }
    __syncthreads();
  }

  if(ACT == 2){
    if(t < 64) rsum[t] = 0.f;
    __syncthreads();
    #pragma unroll
    for(int r=0;r<4;++r){
      int rl0 = wm + lg*4 + r, rl1 = rl0 + 16;
      int c0 = bn + wn + lr, c1 = c0 + 16;
      float v00 = gelu_f(acc00[r] + bias[c0]) * w2[c0];
      float v01 = gelu_f(acc01[r] + bias[c1]) * w2[c1];
      atomicAdd(&rsum[rl0], v00 + v01);
      float v10 = gelu_f(acc10[r] + bias[c0]) * w2[c0];
      float v11 = gelu_f(acc11[r] + bias[c1]) * w2[c1];
      atomicAdd(&rsum[rl1], v10 + v11);
    }
    __syncthreads();
    if(t < 64 && (bm + t) < M) atomicAdd(&vp[bm + t], rsum[t]);
    return;
  }

  size_t zbase = (size_t)z * (size_t)M;
  #pragma unroll
  for(int r=0;r<4;++r){
    int row0 = bm + wm + lg*4 + r;
    int row1 = row0 + 16;
    int c0 = bn + wn + lr, c1 = c0 + 16;
    if(DIRECT){
      if(row0 < M){
        float v0 = acc00[r] + bias[c0], v1 = acc01[r] + bias[c1];
        if(ACT == 1){ v0 = gelu_f(v0); v1 = gelu_f(v1); }
        P[(size_t)row0*N + c0] = v0; P[(size_t)row0*N + c1] = v1;
      }
      if(row1 < M){
        float v0 = acc10[r] + bias[c0], v1 = acc11[r] + bias[c1];
        if(ACT == 1){ v0 = gelu_f(v0); v1 = gelu_f(v1); }
        P[(size_t)row1*N + c0] = v0; P[(size_t)row1*N + c1] = v1;
      }
    } else {
      if(row0 < M){
        P[(zbase+row0)*N + c0] = acc00[r];
        P[(zbase+row0)*N + c1] = acc01[r];
      }
      if(row1 < M){
        P[(zbase+row1)*N + c0] = acc10[r];
        P[(zbase+row1)*N + c1] = acc11[r];
      }
    }
  }
}

// ----------------- row finish: split-K(4) sum + bias + residual (+LN | +out-copy) -----------------
template<bool LN>
__global__ __launch_bounds__(256) void k_finrow(const float* __restrict__ P, const float* __restrict__ bias,
                                                float* __restrict__ vecs, const float* __restrict__ lw,
                                                const float* __restrict__ lb, float* __restrict__ dst){
  __shared__ float red[256];
  int row = blockIdx.x, t = threadIdx.x;
  int j = t*4;
  float4 v = *(const float4*)&P[(size_t)row*HD + j];
  #pragma unroll
  for(int z=1;z<4;++z){
    float4 p = *(const float4*)&P[((size_t)z*SQ + row)*HD + j];
    v.x += p.x; v.y += p.y; v.z += p.z; v.w += p.w;
  }
  float4 b4 = *(const float4*)&bias[j];
  float4 r4 = *(const float4*)&vecs[(size_t)row*HD + j];
  v.x += b4.x + r4.x; v.y += b4.y + r4.y; v.z += b4.z + r4.z; v.w += b4.w + r4.w;
  *(float4*)&vecs[(size_t)row*HD + j] = v;
  if(LN){
    float s = v.x + v.y + v.z + v.w;
    red[t] = s; __syncthreads();
    for(int o=128;o>0;o>>=1){ if(t<o) red[t]+=red[t+o]; __syncthreads(); }
    float m = red[0] * (1.0f/HD);
    __syncthreads();
    float dx = v.x-m, dy = v.y-m, dz = v.z-m, dw = v.w-m;
    red[t] = dx*dx + dy*dy + dz*dz + dw*dw; __syncthreads();
    for(int o=128;o>0;o>>=1){ if(t<o) red[t]+=red[t+o]; __syncthreads(); }
    float denom = sqrtf(red[0] * (1.0f/HD) + 1e-5f);
    float4 w4 = *(const float4*)&lw[j];
    float4 lb4 = *(const float4*)&lb[j];
    float4 o4;
    o4.x = dx/denom*w4.x + lb4.x; o4.y = dy/denom*w4.y + lb4.y;
    o4.z = dz/denom*w4.z + lb4.z; o4.w = dw/denom*w4.w + lb4.w;
    *(float4*)&dst[(size_t)row*HD + j] = o4;
  } else {
    if(row >= 1) *(float4*)&dst[(size_t)(row-1)*HD + j] = v;
  }
}

// ----------------- action value average -> vecs even rows -----------------
__global__ __launch_bounds__(256) void k_finav(const float* __restrict__ Pm, const float* __restrict__ Pt,
                                               const float* __restrict__ bm_, const float* __restrict__ bt_,
                                               const float* __restrict__ pos, float* __restrict__ vecs){
  int i4 = blockIdx.x*256 + threadIdx.x;     // 128*256 float4s
  int k = i4 >> 8, j = (i4 & 255)*4;
  float4 v = {0,0,0,0};
  #pragma unroll
  for(int z=0;z<4;++z){
    float4 a = *(const float4*)&Pm[((size_t)z*KS + k)*HD + j];
    float4 b = *(const float4*)&Pt[((size_t)z*KS + k)*HD + j];
    v.x += a.x + b.x; v.y += a.y + b.y; v.z += a.z + b.z; v.w += a.w + b.w;
  }
  float4 bm4 = *(const float4*)&bm_[j];
  float4 bt4 = *(const float4*)&bt_[j];
  float4 p4 = *(const float4*)&pos[(size_t)(2*k+2)*HD + j];
  float4 o;
  o.x = 0.5f*(v.x + bm4.x + bt4.x) + p4.x;
  o.y = 0.5f*(v.y + bm4.y + bt4.y) + p4.y;
  o.z = 0.5f*(v.z + bm4.z + bt4.z) + p4.z;
  o.w = 0.5f*(v.w + bm4.w + bt4.w) + p4.w;
  *(float4*)&vecs[(size_t)(2*k+2)*HD + j] = o;
}

// ----------------- layernorm (layer-0 ln1 only) -----------------
__global__ void k_ln(const float* __restrict__ in, const float* __restrict__ w, const float* __restrict__ b,
                     float* __restrict__ outp){
  __shared__ float red[256];
  int row = blockIdx.x, t = threadIdx.x;
  const float* xr = in + (size_t)row*HD;
  float s = 0.f;
  for(int i=t;i<HD;i+=256) s += xr[i];
  red[t]=s; __syncthreads();
  for(int o=128;o>0;o>>=1){ if(t<o) red[t]+=red[t+o]; __syncthreads(); }
  float m = red[0] * (1.0f/HD);
  __syncthreads();
  float ss = 0.f;
  for(int i=t;i<HD;i+=256){ float d = xr[i]-m; ss += d*d; }
  red[t]=ss; __syncthreads();
  for(int o=128;o>0;o>>=1){ if(t<o) red[t]+=red[t+o]; __syncthreads(); }
  float var = red[0] * (1.0f/HD);
  float denom = sqrtf(var + 1e-5f);
  for(int i=t;i<HD;i+=256) outp[(size_t)row*HD+i] = (xr[i]-m)/denom * w[i] + b[i];
}

// ----------------- attention -----------------
__global__ void k_attn(const float* __restrict__ qkv, float* __restrict__ outp){
  __shared__ float qv[64];
  __shared__ float p[SQ];
  __shared__ float red[256];
  int q = blockIdx.x, h = blockIdx.y, t = threadIdx.x;
  if(t < 64) qv[t] = qkv[(size_t)q*3072 + h*64 + t];
  __syncthreads();
  int nk = q + 1;
  float lmax = -1e30f;
  for(int j=t;j<nk;j+=256){
    const float* kr = qkv + (size_t)j*3072 + 1024 + h*64;
    float d = 0.f;
    for(int c=0;c<64;++c) d += qv[c]*kr[c];
    d *= 0.125f;
    p[j] = d;
    lmax = fmaxf(lmax, d);
  }
  red[t] = lmax; __syncthreads();
  for(int o=128;o>0;o>>=1){ if(t<o) red[t] = fmaxf(red[t], red[t+o]); __syncthreads(); }
  float m = red[0];
  __syncthreads();
  float lsum = 0.f;
  for(int j=t;j<nk;j+=256){ float e = expf(p[j]-m); p[j] = e; lsum += e; }
  red[t] = lsum; __syncthreads();
  for(int o=128;o>0;o>>=1){ if(t<o) red[t] += red[t+o]; __syncthreads(); }
  float inv = 1.0f/red[0];
  __syncthreads();
  int d = t & 63, g = t >> 6;
  float acc = 0.f;
  for(int j=g;j<nk;j+=4) acc += p[j]*qkv[(size_t)j*3072 + 2048 + h*64 + d];
  red[t] = acc; __syncthreads();
  if(g == 0){
    float o4 = red[d] + red[64+d] + red[128+d] + red[192+d];
    outp[(size_t)q*HD + h*64 + d] = o4*inv;
  }
}

// ----------------- final small outputs -----------------
__global__ void k_outsmall(const float* __restrict__ vp, const float* __restrict__ b2,
                           const float* __restrict__ rew, float* __restrict__ outp){
  int t = threadIdx.x;
  float bb = b2[0];
  if(t == 0) outp[OUT_VP] = vp[KS] + bb;
  if(t < KS){
    float d = (vp[t] + bb) - rew[t];
    outp[OUT_LOSS + t] = d*d;
    outp[OUT_REWO + t] = rew[t];
  }
}

extern "C" void kernel_launch(void* const* d_in, const int* in_sizes, int n_in,
                              void* d_out, int out_size, void* d_ws, size_t ws_size,
                              hipStream_t stream){
  const float* x     = (const float*)d_in[0];
  const float* mv    = (const float*)d_in[1];
  const float* mnv   = (const float*)d_in[2];
  const float* surp  = (const float*)d_in[3];
  const float* mrew  = (const float*)d_in[4];
  const float* noise = (const float*)d_in[5];
  const int*   aim   = (const int*)d_in[6];
  const int*   ait   = (const int*)d_in[7];
  const float* start = (const float*)d_in[8];
  const float* pos   = (const float*)d_in[9];
  const float* inW = (const float*)d_in[10]; const float* inB = (const float*)d_in[11];
  const float* oW  = (const float*)d_in[12]; const float* oB  = (const float*)d_in[13];
  const float* l1w = (const float*)d_in[14]; const float* l1b = (const float*)d_in[15];
  const float* l2w = (const float*)d_in[16]; const float* l2b = (const float*)d_in[17];
  const float* f1w = (const float*)d_in[18]; const float* f1b = (const float*)d_in[19];
  const float* f2w = (const float*)d_in[20]; const float* f2b = (const float*)d_in[21];
  const float* amw1= (const float*)d_in[22]; const float* amb1= (const float*)d_in[23];
  const float* amw2= (const float*)d_in[24]; const float* amb2= (const float*)d_in[25];
  const float* atw1= (const float*)d_in[26]; const float* atb1= (const float*)d_in[27];
  const float* atw2= (const float*)d_in[28]; const float* atb2= (const float*)d_in[29];
  const float* vw1 = (const float*)d_in[30]; const float* vb1 = (const float*)d_in[31];
  const float* vw2 = (const float*)d_in[32]; const float* vb2 = (const float*)d_in[33];

  float* out = (float*)d_out;
  char* ws = (char*)d_ws;
  u32*  hist3 = (u32*)(ws+OFF_H3);
  u32*  cnt3  = (u32*)(ws+OFF_C3);
  u32*  histS = (u32*)(ws+OFF_HS);
  float* vp   = (float*)(ws+OFF_VP);
  u32*  pref3 = (u32*)(ws+OFF_P3);
  u32*  keys3 = (u32*)(ws+OFF_K3);
  u32*  lo3   = (u32*)(ws+OFF_L3);
  u32*  keysS = (u32*)(ws+OFF_KSC);
  u64*  cand  = (u64*)(ws+OFF_CAND);
  Ctrl* ctrl  = (Ctrl*)(ws+OFF_CTRL);
  int*  idxb  = (int*)(ws+OFF_IDX);
  float* hm   = (float*)(ws+OFF_HM);
  float* ht   = (float*)(ws+OFF_HT);
  float* rew  = (float*)(ws+OFF_REW);
  float* vecs = (float*)(ws+OFF_VECS);
  float* lnb  = (float*)(ws+OFF_LNB);
  float* qkvb = (float*)(ws+OFF_QKV);
  float* attn = (float*)(ws+OFF_ATT);
  float* ffh  = (float*)(ws+OFF_FFH);
  float* part = (float*)(ws+OFF_PART);
  float* part2= part + (size_t)4*SQ*HD;

  dim3 b256(256);
  int gN = NM/256;

  (void)hipMemsetAsync(ws, 0, ZERO_BYTES, stream);

  // ---- scoring / ranking / top-k ----
  hipLaunchKernelGGL(k_sim2key, dim3(NM/4), b256, 0, stream, mv, x, surp, noise, keys3, hist3);
  hipLaunchKernelGGL(k_scan3, dim3(3), dim3(1024), 0, stream, hist3, pref3);
  hipLaunchKernelGGL(k_scatter3, dim3(gN), b256, 0, stream, keys3, pref3, cnt3, lo3);
  hipLaunchKernelGGL(k_rank3score, dim3(gN), b256, 0, stream, keys3, pref3, lo3, keysS, histS);
  hipLaunchKernelGGL(k_sel1, dim3(1), dim3(1024), 0, stream, histS, ctrl);
  hipLaunchKernelGGL(k_collect, dim3(gN), b256, 0, stream, keysS, ctrl, cand);
  hipLaunchKernelGGL(k_sortsel, dim3(1), dim3(1024), 0, stream, cand, ctrl, idxb);

  // ---- GEMM helper ----
  auto gemm = [&](const float* A, const float* Bw, const float* bias, float* C,
                  int M, int N, int K, int S, int act, int lda){
    int nbm = (M + 63) / 64, nbn = N / 64;
    if(S == 1){
      int nwg = nbm * nbn;
      if(act == 1)
        hipLaunchKernelGGL((gemm_k<1,true>), dim3(nwg), b256, 0, stream, A, Bw, bias, C, (const float*)nullptr, (float*)nullptr, M, N, K, 1, nbm, lda);
      else
        hipLaunchKernelGGL((gemm_k<0,true>), dim3(nwg), b256, 0, stream, A, Bw, bias, C, (const float*)nullptr, (float*)nullptr, M, N, K, 1, nbm, lda);
    } else {
      int nwg = nbm * nbn * S;
      hipLaunchKernelGGL((gemm_k<0,false>), dim3(nwg), b256, 0, stream, A, Bw, bias, C, (const float*)nullptr, (float*)nullptr, M, N, K, S, nbm, lda);
    }
  };

  // ---- gather + action MLPs + sequence assembly ----
  hipLaunchKernelGGL(k_gather, dim3(KS+1), b256, 0, stream, idxb, mv, mnv, mrew, aim, ait,
                     amw1, amb1, atw1, atb1, start, x, pos,
                     vecs, out + OUT_NEXT, hm, ht, rew, out + OUT_REWO);
  gemm(hm, amw2, nullptr, part,  KS, HD, HD, 4, 0, HD);
  gemm(ht, atw2, nullptr, part2, KS, HD, HD, 4, 0, HD);
  hipLaunchKernelGGL(k_finav, dim3(KS), b256, 0, stream, part, part2, amb2, atb2, pos, vecs);
  hipLaunchKernelGGL(k_ln, dim3(SQ), b256, 0, stream, vecs, l1w, l1b, lnb);

  // ---- transformer ----
  for(int l=0;l<NL;++l){
    gemm(lnb, inW + (size_t)l*3*HD*HD, inB + (size_t)l*3*HD, qkvb, SQ, 3*HD, HD, 1, 0, HD);
    hipLaunchKernelGGL(k_attn, dim3(SQ, NH_), b256, 0, stream, qkvb, attn);
    gemm(attn, oW + (size_t)l*HD*HD, nullptr, part, SQ, HD, HD, 4, 0, HD);
    hipLaunchKernelGGL((k_finrow<true>), dim3(SQ), b256, 0, stream, part, oB + (size_t)l*HD, vecs,
                       l2w + (size_t)l*HD, l2b + (size_t)l*HD, lnb);
    gemm(lnb, f1w + (size_t)l*4*HD*HD, f1b + (size_t)l*4*HD, ffh, SQ, 4*HD, HD, 1, 1, HD);
    gemm(ffh, f2w + (size_t)l*HD*4*HD, nullptr, part, SQ, HD, 4*HD, 4, 0, 4*HD);
    if(l < NL-1)
      hipLaunchKernelGGL((k_finrow<true>), dim3(SQ), b256, 0, stream, part, f2b + (size_t)l*HD, vecs,
                         l1w + (size_t)(l+1)*HD, l1b + (size_t)(l+1)*HD, lnb);
    else
      hipLaunchKernelGGL((k_finrow<false>), dim3(SQ), b256, 0, stream, part, f2b + (size_t)l*HD, vecs,
                         (const float*)nullptr, (const float*)nullptr, out);
  }

  // ---- value head (vp via in-kernel row-dot atomics) + small outputs ----
  {
    int nbm = 3, nbn = 4*HD/64;
    hipLaunchKernelGGL((gemm_k<2,true>), dim3(nbm*nbn), b256, 0, stream,
                       vecs + HD, vw1, vb1, (float*)nullptr, vw2, vp, KS+1, 4*HD, HD, 1, nbm, 2*HD);
  }
  hipLaunchKernelGGL(k_outsmall, dim3(1), b256, 0, stream, vp, vb2, rew, out);
}